// Round 15
// baseline (2688.387 us; speedup 1.0000x reference)
//
#include <hip/hip_runtime.h>
#include <hip/hip_fp16.h>
#include <cstdint>

// Problem constants
#define T_  256
#define B_  64
#define I_  1024
#define H_  1024
#define E_  4
#define C_  128
#define G4  4096   // 4*H

typedef _Float16 f16;
typedef _Float16 f16x2 __attribute__((ext_vector_type(2)));
typedef _Float16 f16x8 __attribute__((ext_vector_type(8)));
typedef float    f32x4 __attribute__((ext_vector_type(4)));

__device__ __forceinline__ float sigmoidf_(float x) { return 1.f / (1.f + __expf(-x)); }

union pk2 { uint32_t u; f16x2 h; };

// ---------------- conversion f32 -> f16 (vectorized, grid-stride) -------------
__global__ void k_f32_to_f16(const float* __restrict__ src, f16* __restrict__ dst, int n8) {
    int i = blockIdx.x * blockDim.x + threadIdx.x;
    int stride = gridDim.x * blockDim.x;
    for (; i < n8; i += stride) {
        const float4* s = reinterpret_cast<const float4*>(src) + (size_t)i * 2;
        float4 a = s[0], b = s[1];
        f16x8 v = { (f16)a.x, (f16)a.y, (f16)a.z, (f16)a.w,
                    (f16)b.x, (f16)b.y, (f16)b.z, (f16)b.w };
        *reinterpret_cast<f16x8*>(dst + (size_t)i * 8) = v;
    }
}

// ---------------- mixed biases: gbias = coef@(bi+bh), bom = coef@bo ----------
__global__ void k_mix_biases(const float* __restrict__ coef, const float* __restrict__ bi,
                             const float* __restrict__ bh, const float* __restrict__ bo,
                             float* __restrict__ gbias, float* __restrict__ bom) {
    int idx = blockIdx.x * blockDim.x + threadIdx.x;
    int stride = gridDim.x * blockDim.x;
    for (int i = idx; i < B_ * G4; i += stride) {
        int b = i >> 12, o = i & (G4 - 1);
        float s = 0.f;
#pragma unroll
        for (int e = 0; e < 4; ++e) s += coef[b * 4 + e] * (bi[e * G4 + o] + bh[e * G4 + o]);
        gbias[i] = s;
    }
    for (int i = idx; i < B_ * C_; i += stride) {
        int b = i >> 7, c = i & (C_ - 1);
        float s = 0.f;
#pragma unroll
        for (int e = 0; e < 4; ++e) s += coef[b * 4 + e] * bo[e * C_ + c];
        bom[i] = s;
    }
}

// ---------------- h0 -> f16 --------------------------------------------------
__global__ void k_init_h0h(const float* __restrict__ h0, f16* __restrict__ h0h) {
    int i = blockIdx.x * blockDim.x + threadIdx.x;
    if (i < B_ * H_) h0h[i] = (f16)h0[i];
}

// ---------------- xi GEMM: per-sample mixed input projection -----------------
template<bool XF16, bool WF16>
__global__ __launch_bounds__(256, 1) void k_xi_gemm(
        const f16* __restrict__ xh, const float* __restrict__ xf,
        const f16* __restrict__ Wih, const float* __restrict__ Wif,
        const float* __restrict__ coef, const float* __restrict__ gbias,
        f16* __restrict__ xi) {
    __shared__ f16 As[256 * 72];
    __shared__ f16 Bs[128 * 72];
    const int nt = blockIdx.x;      // 0..31  (128-col tile of 4096)
    const int b  = blockIdx.y;      // 0..63
    const int tid = threadIdx.x;
    const int lane = tid & 63, wave = tid >> 6;
    const int wr = wave >> 1, wc = wave & 1;

    float cf[4];
#pragma unroll
    for (int e = 0; e < 4; ++e) cf[e] = coef[b * 4 + e];

    f32x4 acc[8][4];
#pragma unroll
    for (int mi = 0; mi < 8; ++mi)
#pragma unroll
        for (int ni = 0; ni < 4; ++ni) acc[mi][ni] = 0.f;

    for (int kk = 0; kk < I_; kk += 64) {
        __syncthreads();
#pragma unroll
        for (int it = 0; it < 8; ++it) {
            int chunk = it * 256 + tid;
            int row = chunk >> 3, c8 = chunk & 7;
            if constexpr (XF16) {
                *reinterpret_cast<f16x8*>(&As[row * 72 + c8 * 8]) =
                    *reinterpret_cast<const f16x8*>(&xh[((size_t)row * B_ + b) * I_ + kk + c8 * 8]);
            } else {
                const float4* p = reinterpret_cast<const float4*>(&xf[((size_t)row * B_ + b) * I_ + kk + c8 * 8]);
                float4 a = p[0], bq = p[1];
                f16x8 v = { (f16)a.x, (f16)a.y, (f16)a.z, (f16)a.w,
                            (f16)bq.x, (f16)bq.y, (f16)bq.z, (f16)bq.w };
                *reinterpret_cast<f16x8*>(&As[row * 72 + c8 * 8]) = v;
            }
        }
#pragma unroll
        for (int it = 0; it < 4; ++it) {
            int chunk = it * 256 + tid;
            int n = chunk >> 3, c8 = chunk & 7;
            if constexpr (WF16) {
                size_t base = ((size_t)(nt * 128 + n)) * I_ + kk + c8 * 8;
                f16 c0 = (f16)cf[0], c1 = (f16)cf[1], c2 = (f16)cf[2], c3 = (f16)cf[3];
                f16x8 w0 = *reinterpret_cast<const f16x8*>(&Wih[base]);
                f16x8 w1 = *reinterpret_cast<const f16x8*>(&Wih[base + (size_t)1 * G4 * I_]);
                f16x8 w2 = *reinterpret_cast<const f16x8*>(&Wih[base + (size_t)2 * G4 * I_]);
                f16x8 w3 = *reinterpret_cast<const f16x8*>(&Wih[base + (size_t)3 * G4 * I_]);
                f16x8 m = w0 * c0 + w1 * c1 + w2 * c2 + w3 * c3;
                *reinterpret_cast<f16x8*>(&Bs[n * 72 + c8 * 8]) = m;
            } else {
                size_t base = ((size_t)(nt * 128 + n)) * I_ + kk + c8 * 8;
                float m[8];
#pragma unroll
                for (int j = 0; j < 8; ++j) m[j] = 0.f;
#pragma unroll
                for (int e = 0; e < 4; ++e) {
                    const float4* p = reinterpret_cast<const float4*>(&Wif[base + (size_t)e * G4 * I_]);
                    float4 a = p[0], bq = p[1];
                    m[0] += cf[e] * a.x;  m[1] += cf[e] * a.y;
                    m[2] += cf[e] * a.z;  m[3] += cf[e] * a.w;
                    m[4] += cf[e] * bq.x; m[5] += cf[e] * bq.y;
                    m[6] += cf[e] * bq.z; m[7] += cf[e] * bq.w;
                }
                f16x8 v = { (f16)m[0], (f16)m[1], (f16)m[2], (f16)m[3],
                            (f16)m[4], (f16)m[5], (f16)m[6], (f16)m[7] };
                *reinterpret_cast<f16x8*>(&Bs[n * 72 + c8 * 8]) = v;
            }
        }
        __syncthreads();
#pragma unroll
        for (int ks = 0; ks < 2; ++ks) {
            int ko = ks * 32 + (lane >> 4) * 8;
            f16x8 a[8], bb[4];
#pragma unroll
            for (int mi = 0; mi < 8; ++mi)
                a[mi] = *reinterpret_cast<const f16x8*>(&As[(wr * 128 + mi * 16 + (lane & 15)) * 72 + ko]);
#pragma unroll
            for (int ni = 0; ni < 4; ++ni)
                bb[ni] = *reinterpret_cast<const f16x8*>(&Bs[(wc * 64 + ni * 16 + (lane & 15)) * 72 + ko]);
#pragma unroll
            for (int mi = 0; mi < 8; ++mi)
#pragma unroll
                for (int ni = 0; ni < 4; ++ni)
                    acc[mi][ni] = __builtin_amdgcn_mfma_f32_16x16x32_f16(a[mi], bb[ni], acc[mi][ni], 0, 0, 0);
        }
    }
#pragma unroll
    for (int mi = 0; mi < 8; ++mi)
#pragma unroll
        for (int ni = 0; ni < 4; ++ni)
#pragma unroll
            for (int j = 0; j < 4; ++j) {
                int t = wr * 128 + mi * 16 + (lane >> 4) * 4 + j;
                int o = nt * 128 + wc * 64 + ni * 16 + (lane & 15);
                float v = acc[mi][ni][j] + gbias[b * G4 + o];
                xi[((size_t)t * B_ + b) * G4 + o] = (f16)v;
            }
}

// ---------------- barrier V3 (R11..R14-proven; raw blockIdx) -----------------
__device__ __forceinline__ void grid_barrier3(int* __restrict__ arr, int* __restrict__ go,
                                              int t, int bid) {
    __syncthreads();
    const int tid = threadIdx.x;
    if (bid == 0) {
        if (tid >= 1 && tid < 256) {              // parallel sweep, own slot each
            while (__hip_atomic_load(&arr[t * 256 + tid], __ATOMIC_RELAXED,
                                     __HIP_MEMORY_SCOPE_AGENT) == 0)
                __builtin_amdgcn_s_sleep(1);
        }
        __syncthreads();
        if (tid == 0)                             // publish master's own h (release)
            __hip_atomic_store(&go[t * 512 + 511], 1, __ATOMIC_RELEASE,
                               __HIP_MEMORY_SCOPE_AGENT);
        __syncthreads();
        if (tid < 32)                             // fan-out go: 32 lines, 8 spinners each
            __hip_atomic_store(&go[t * 512 + tid * 16], 1, __ATOMIC_RELAXED,
                               __HIP_MEMORY_SCOPE_AGENT);
        __syncthreads();
    } else {
        if (tid == 0) {
            __hip_atomic_store(&arr[t * 256 + bid], 1, __ATOMIC_RELEASE,
                               __HIP_MEMORY_SCOPE_AGENT);
            while (__hip_atomic_load(&go[t * 512 + (bid >> 3) * 16], __ATOMIC_RELAXED,
                                     __HIP_MEMORY_SCOPE_AGENT) == 0)
                __builtin_amdgcn_s_sleep(1);
        }
        __builtin_amdgcn_sched_barrier(0);
        __syncthreads();
    }
}

// ---------------- persistent recurrence (cooperative, 256 x 512) -------------
// R14 core + two deltas:
//  (1) 8-deep A-prefetch pipeline (pfa..pfh named rotation; LDS write stays
//      1-ahead double-buffer) -> exposed h_prev read latency per tile halves.
//  (2) h and gate-0 cross-step traffic moves via 4-byte AGENT-scope relaxed
//      atomics (serviced at the L3 coherence point: no HBM round trip, no
//      wbl2, no L2 fill -> the cached-h_prev staleness audit is unchanged).
//      Epilogue remapped to 128 threads x 2 adjacent cols for 4B alignment.
// Everything else identical to R14 (XCD swizzle, cached h_prev PRE, barrier
// V3, W in swizzled LDS, gate double-buffer).
#define POOL_SZ  148480
#define AS0_OFF  131072
#define AS1_OFF  (131072 + 8192)
#define GL_OFF   131072

#define BF(KC, KS) (*reinterpret_cast<const f16x8*>(pool + wrow + (KC) * 128 + (((KS) * 64 + koff) ^ swz)))

// cached A-tile prefetch: tile KC into named reg PF
#define PRE(KC, PF) PF = *reinterpret_cast<const f16x8*>(&hprev[(size_t)sr * hstr + (KC) * 64 + soct * 8]);

#define AFR(AOFF, AROW, KS) (*reinterpret_cast<const f16x8*>(pool + (AOFF) + (AROW) + (((KS) * 64 + koff) ^ swz)))

#define MM4(ROFF) \
    acc0 = __builtin_amdgcn_mfma_f32_16x16x32_f16(AFR(ROFF, arow0, 0), bq0, acc0, 0, 0, 0); \
    acc1 = __builtin_amdgcn_mfma_f32_16x16x32_f16(AFR(ROFF, arow1, 0), bq0, acc1, 0, 0, 0); \
    acc0 = __builtin_amdgcn_mfma_f32_16x16x32_f16(AFR(ROFF, arow0, 1), bq1, acc0, 0, 0, 0); \
    acc1 = __builtin_amdgcn_mfma_f32_16x16x32_f16(AFR(ROFF, arow1, 1), bq1, acc1, 0, 0, 0);

// body KC (KC<8): MFMA(KC) from ROFF, write tile KC+1 (PFW), prefetch KC+8 (PFL)
#define KSTP(KC, ROFF, WOFF, PFW, PFL) { \
    const f16x8 bq0 = BF(KC, 0), bq1 = BF(KC, 1); \
    PRE((KC) + 8, PFL); \
    MM4(ROFF); \
    *reinterpret_cast<f16x8*>(pool + (WOFF) + sdst) = PFW; \
    __syncthreads(); \
}
// body KC (8<=KC<15): no prefetch
#define KST(KC, ROFF, WOFF, PFW) { \
    const f16x8 bq0 = BF(KC, 0), bq1 = BF(KC, 1); \
    MM4(ROFF); \
    *reinterpret_cast<f16x8*>(pool + (WOFF) + sdst) = PFW; \
    __syncthreads(); \
}

__global__ __launch_bounds__(512, 1) void k_rec_persist(
        const float* __restrict__ Wh, const f16* __restrict__ h0h,
        const float* __restrict__ c0, f16* xi, const float* __restrict__ coef,
        float* __restrict__ out, int* __restrict__ arr, int* __restrict__ go) {
    __shared__ __attribute__((aligned(16))) char pool[POOL_SZ];
    float* gl = reinterpret_cast<float*>(pool + GL_OFF);   // [4][64][17]

    const int bid = blockIdx.x;
    const int jb = ((bid & 7) << 5) | (bid >> 3);          // XCD-contiguous cols
    const int tid = threadIdx.x, lane = tid & 63, w = tid >> 6;
    const int ex = w & 3, mh = w >> 2;                    // expert, M-half
    const int l15 = lane & 15, hi8 = (lane >> 4) * 8;

    // ---- one-time: Wh slice f32 -> f16 into swizzled LDS ----
    for (int i = tid; i < 8192; i += 512) {
        int r = i >> 7, oct = i & 127;                    // r = e*16+g*4+c
        int e = r >> 4, g = (r >> 2) & 3, c = r & 3;
        const float* src = &Wh[((size_t)e * G4 + g * H_ + jb * 4 + c) * H_ + oct * 8];
        float4 f0 = *reinterpret_cast<const float4*>(src);
        float4 f1 = *reinterpret_cast<const float4*>(src + 4);
        f16x8 v = { (f16)f0.x, (f16)f0.y, (f16)f0.z, (f16)f0.w,
                    (f16)f1.x, (f16)f1.y, (f16)f1.z, (f16)f1.w };
        int db = r * 2048 + ((oct * 16) ^ ((r & 7) << 4));
        *reinterpret_cast<f16x8*>(pool + db) = v;
    }

    // cell-update identity: 128 threads x 2 adjacent cols (4B-aligned pairs)
    const int bb = tid >> 1, pr = tid & 1;
    const int cp0 = jb * 4 + pr * 2;                      // first col of pair
    float c_reg0 = 0.f, c_reg1 = 0.f;
    float4 cf4 = {0.f, 0.f, 0.f, 0.f};
    if (tid < 128) {
        c_reg0 = c0[bb * H_ + cp0];
        c_reg1 = c0[bb * H_ + cp0 + 1];
        cf4 = *reinterpret_cast<const float4*>(&coef[bb * 4]);
    }

    // per-thread LDS bases; swizzle applied to FULL within-row offset at use
    const int swz   = (l15 & 7) << 4;
    const int koff  = hi8 * 2;
    const int wrow  = (ex * 16 + l15) * 2048;
    const int arow0 = (mh * 32 + l15) * 128;
    const int arow1 = arow0 + 16 * 128;
    const int sr = tid >> 3, soct = tid & 7;
    const int sdst = sr * 128 + ((soct * 16) ^ ((sr & 7) << 4));

    __syncthreads();

    // gate double-buffer: step-0 gates (gate0 via 4B agent atomic: overlay line)
    float xgc0a = 0.f, xgc0b = 0.f, xgc1a = 0.f, xgc1b = 0.f;
    float xgc2a = 0.f, xgc2b = 0.f, xgc3a = 0.f, xgc3b = 0.f;
    if (tid < 128) {
        const f16* xp = &xi[((size_t)0 * B_ + bb) * G4 + cp0];
        pk2 p0; p0.u = __hip_atomic_load(reinterpret_cast<const uint32_t*>(xp),
                                         __ATOMIC_RELAXED, __HIP_MEMORY_SCOPE_AGENT);
        xgc0a = (float)p0.h.x; xgc0b = (float)p0.h.y;
        f16x2 g1 = *reinterpret_cast<const f16x2*>(xp + H_);
        f16x2 g2 = *reinterpret_cast<const f16x2*>(xp + 2 * H_);
        f16x2 g3 = *reinterpret_cast<const f16x2*>(xp + 3 * H_);
        xgc1a = (float)g1.x; xgc1b = (float)g1.y;
        xgc2a = (float)g2.x; xgc2b = (float)g2.y;
        xgc3a = (float)g3.x; xgc3b = (float)g3.y;
    }

    for (int t = 0; t < T_; ++t) {
        const f16* hprev = (t == 0) ? h0h : (xi + (size_t)(t - 1) * B_ * G4);
        const size_t hstr = (t == 0) ? (size_t)H_ : (size_t)G4;

        // prologue: 8-deep prefetch of tiles 0..7
        f16x8 pfa, pfb, pfc, pfd, pfe, pff, pfg, pfh;
        PRE(0, pfa) PRE(1, pfb) PRE(2, pfc) PRE(3, pfd)
        PRE(4, pfe) PRE(5, pff) PRE(6, pfg) PRE(7, pfh)

        // prefetch NEXT step's gates (consumed at t+1; issued after A-tile PREs)
        float xgn0a = 0.f, xgn0b = 0.f, xgn1a = 0.f, xgn1b = 0.f;
        float xgn2a = 0.f, xgn2b = 0.f, xgn3a = 0.f, xgn3b = 0.f;
        if (t + 1 < T_ && tid < 128) {
            const f16* xq = &xi[((size_t)(t + 1) * B_ + bb) * G4 + cp0];
            pk2 p0; p0.u = __hip_atomic_load(reinterpret_cast<const uint32_t*>(xq),
                                             __ATOMIC_RELAXED, __HIP_MEMORY_SCOPE_AGENT);
            xgn0a = (float)p0.h.x; xgn0b = (float)p0.h.y;
            f16x2 g1 = *reinterpret_cast<const f16x2*>(xq + H_);
            f16x2 g2 = *reinterpret_cast<const f16x2*>(xq + 2 * H_);
            f16x2 g3 = *reinterpret_cast<const f16x2*>(xq + 3 * H_);
            xgn1a = (float)g1.x; xgn1b = (float)g1.y;
            xgn2a = (float)g2.x; xgn2b = (float)g2.y;
            xgn3a = (float)g3.x; xgn3b = (float)g3.y;
        }

        *reinterpret_cast<f16x8*>(pool + AS0_OFF + sdst) = pfa;   // tile 0
        f32x4 acc0 = {0.f, 0.f, 0.f, 0.f}, acc1 = {0.f, 0.f, 0.f, 0.f};
        __syncthreads();

        KSTP(0,  AS0_OFF, AS1_OFF, pfb, pfa)   // load tile 8
        KSTP(1,  AS1_OFF, AS0_OFF, pfc, pfb)   // tile 9
        KSTP(2,  AS0_OFF, AS1_OFF, pfd, pfc)   // tile 10
        KSTP(3,  AS1_OFF, AS0_OFF, pfe, pfd)   // tile 11
        KSTP(4,  AS0_OFF, AS1_OFF, pff, pfe)   // tile 12
        KSTP(5,  AS1_OFF, AS0_OFF, pfg, pff)   // tile 13
        KSTP(6,  AS0_OFF, AS1_OFF, pfh, pfg)   // tile 14
        KSTP(7,  AS1_OFF, AS0_OFF, pfa, pfh)   // tile 15
        KST(8,   AS0_OFF, AS1_OFF, pfb)
        KST(9,   AS1_OFF, AS0_OFF, pfc)
        KST(10,  AS0_OFF, AS1_OFF, pfd)
        KST(11,  AS1_OFF, AS0_OFF, pfe)
        KST(12,  AS0_OFF, AS1_OFF, pff)
        KST(13,  AS1_OFF, AS0_OFF, pfg)
        KST(14,  AS0_OFF, AS1_OFF, pfh)
        // tile 15: MFMA only + trailing sync (gl overlay becomes safe)
        {
            const f16x8 bq0 = BF(15, 0), bq1 = BF(15, 1);
            MM4(AS1_OFF);
            __syncthreads();
        }

        // park per-expert partials into gl (overlays As0/As1)
#pragma unroll
        for (int j = 0; j < 4; ++j) {
            int r0 = mh * 32 + (lane >> 4) * 4 + j;
            gl[(ex * 64 + r0) * 17 + l15]      = acc0[j];
            gl[(ex * 64 + r0 + 16) * 17 + l15] = acc1[j];
        }
        __syncthreads();

        // mix experts + cell update (128 threads x 2 cols); 4B agent-atomic h store
        if (tid < 128) {
            float ga[4], gb[4];
#pragma unroll
            for (int g = 0; g < 4; ++g) {
                int nn = g * 4 + pr * 2;
                ga[g] = cf4.x * gl[(0 * 64 + bb) * 17 + nn] +
                        cf4.y * gl[(1 * 64 + bb) * 17 + nn] +
                        cf4.z * gl[(2 * 64 + bb) * 17 + nn] +
                        cf4.w * gl[(3 * 64 + bb) * 17 + nn];
                gb[g] = cf4.x * gl[(0 * 64 + bb) * 17 + nn + 1] +
                        cf4.y * gl[(1 * 64 + bb) * 17 + nn + 1] +
                        cf4.z * gl[(2 * 64 + bb) * 17 + nn + 1] +
                        cf4.w * gl[(3 * 64 + bb) * 17 + nn + 1];
            }
            ga[0] += xgc0a; ga[1] += xgc1a; ga[2] += xgc2a; ga[3] += xgc3a;
            gb[0] += xgc0b; gb[1] += xgc1b; gb[2] += xgc2b; gb[3] += xgc3b;
            float cn0 = sigmoidf_(ga[1]) * c_reg0 + sigmoidf_(ga[0]) * tanhf(ga[2]);
            float hn0 = sigmoidf_(ga[3]) * tanhf(cn0);
            float cn1 = sigmoidf_(gb[1]) * c_reg1 + sigmoidf_(gb[0]) * tanhf(gb[2]);
            float hn1 = sigmoidf_(gb[3]) * tanhf(cn1);
            c_reg0 = cn0; c_reg1 = cn1;
            pk2 st; st.h.x = (f16)hn0; st.h.y = (f16)hn1;
            __hip_atomic_store(reinterpret_cast<uint32_t*>(&xi[((size_t)t * B_ + bb) * G4 + cp0]),
                               st.u, __ATOMIC_RELAXED, __HIP_MEMORY_SCOPE_AGENT);
            if (t == T_ - 1) {
                out[(size_t)T_ * B_ * C_ + bb * H_ + cp0]     = hn0;
                out[(size_t)T_ * B_ * C_ + bb * H_ + cp0 + 1] = hn1;
                out[(size_t)T_ * B_ * C_ + B_ * H_ + bb * H_ + cp0]     = cn0;
                out[(size_t)T_ * B_ * C_ + B_ * H_ + bb * H_ + cp0 + 1] = cn1;
            }
        }
        xgc0a = xgn0a; xgc0b = xgn0b; xgc1a = xgn1a; xgc1b = xgn1b;
        xgc2a = xgn2a; xgc2b = xgn2b; xgc3a = xgn3a; xgc3b = xgn3b;
        if (t != T_ - 1) grid_barrier3(arr, go, t, bid);
    }
}

// ---------------- output projection ------------------------------------------
__global__ __launch_bounds__(256, 1) void k_out_gemm(
        const f16* __restrict__ hs, const f16* __restrict__ Woh,
        const float* __restrict__ coef, const float* __restrict__ bom,
        float* __restrict__ out) {
    __shared__ f16 As[64 * 72];
    __shared__ f16 Bs[256 * 72];
    __shared__ float cfs[64][4];
    const int nt = blockIdx.x;   // 0..1
    const int t  = blockIdx.y;   // 0..255
    const int tid = threadIdx.x, lane = tid & 63, w = tid >> 6;
    cfs[tid >> 2][tid & 3] = coef[tid];

    f32x4 acc[4][4];
#pragma unroll
    for (int e = 0; e < 4; ++e)
#pragma unroll
        for (int mi = 0; mi < 4; ++mi) acc[e][mi] = 0.f;

    for (int kk = 0; kk < H_; kk += 64) {
        __syncthreads();
#pragma unroll
        for (int it = 0; it < 2; ++it) {   // A: hs[t] 64x64 (stride G4 overlay)
            int chunk = it * 256 + tid;
            int row = chunk >> 3, c8 = chunk & 7;
            *reinterpret_cast<f16x8*>(&As[row * 72 + c8 * 8]) =
                *reinterpret_cast<const f16x8*>(&hs[((size_t)t * B_ + row) * G4 + kk + c8 * 8]);
        }
#pragma unroll
        for (int it = 0; it < 8; ++it) {   // B: Wo rows e*C + nt*64 + n
            int chunk = it * 256 + tid;
            int r = chunk >> 3, c8 = chunk & 7;
            int e = r >> 6, nn = r & 63;
            size_t grow = (size_t)e * C_ + nt * 64 + nn;
            *reinterpret_cast<f16x8*>(&Bs[r * 72 + c8 * 8]) =
                *reinterpret_cast<const f16x8*>(&Woh[grow * H_ + kk + c8 * 8]);
        }
        __syncthreads();
#pragma unroll
        for (int ks = 0; ks < 2; ++ks) {
            int ko = ks * 32 + (lane >> 4) * 8;
            f16x8 a[4];
#pragma unroll
            for (int mi = 0; mi < 4; ++mi)
                a[mi] = *reinterpret_cast<const f16x8*>(&As[(mi * 16 + (lane & 15)) * 72 + ko]);
#pragma unroll
            for (int e = 0; e < 4; ++e) {
                f16x8 bf = *reinterpret_cast<const f16x8*>(&Bs[(e * 64 + w * 16 + (lane & 15)) * 72 + ko]);
#pragma unroll
                for (int mi = 0; mi < 4; ++mi)
                    acc[e][mi] = __builtin_amdgcn_mfma_f32_16x16x32_f16(a[mi], bf, acc[e][mi], 0, 0, 0);
            }
        }
    }
#pragma unroll
    for (int mi = 0; mi < 4; ++mi)
#pragma unroll
        for (int j = 0; j < 4; ++j) {
            int bb = mi * 16 + (lane >> 4) * 4 + j;
            int cc = nt * 64 + w * 16 + (lane & 15);
            float v = cfs[bb][0] * acc[0][mi][j] + cfs[bb][1] * acc[1][mi][j] +
                      cfs[bb][2] * acc[2][mi][j] + cfs[bb][3] * acc[3][mi][j];
            v += bom[bb * C_ + cc];
            out[((size_t)t * B_ + bb) * C_ + cc] = v;
        }
}

extern "C" void kernel_launch(void* const* d_in, const int* in_sizes, int n_in,
                              void* d_out, int out_size, void* d_ws, size_t ws_size,
                              hipStream_t stream) {
    const float* x    = (const float*)d_in[0];
    const float* h0   = (const float*)d_in[1];
    const float* c0   = (const float*)d_in[2];
    const float* coef = (const float*)d_in[3];
    const float* Wi   = (const float*)d_in[4];
    const float* bi   = (const float*)d_in[5];
    const float* Wh   = (const float*)d_in[6];
    const float* bh   = (const float*)d_in[7];
    const float* Wo   = (const float*)d_in[8];
    const float* bo   = (const float*)d_in[9];
    float* out = (float*)d_out;

    char* base = (char*)d_ws;
    size_t off = 0;
    auto carve = [&](size_t bytes) -> char* {
        char* r = base + off;
        off = (off + bytes + 255) & ~(size_t)255;
        return r;
    };
    const size_t SZ_XI  = (size_t)T_ * B_ * G4 * 2;   // 134.2 MB (gate-0 doubles as hs)
    const size_t SZ_WOH = (size_t)E_ * C_ * H_ * 2;   // 1 MB
    const size_t SZ_ARR = (size_t)T_ * 256 * 4;       // arrival slots
    const size_t SZ_GO  = (size_t)T_ * 512 * 4;       // go fan-out lines
    const size_t SZ_WIH = (size_t)E_ * G4 * I_ * 2;   // 33.5 MB (optional)
    const size_t SZ_XH  = (size_t)T_ * B_ * I_ * 2;   // 33.5 MB (optional)

    f16*   xi     = (f16*)carve(SZ_XI);
    f16*   Woh    = (f16*)carve(SZ_WOH);
    f16*   h0h    = (f16*)carve((size_t)B_ * H_ * 2);
    float* gbias  = (float*)carve((size_t)B_ * G4 * 4);
    float* bom    = (float*)carve((size_t)B_ * C_ * 4);
    int*   arr    = (int*)carve(SZ_ARR);
    int*   go     = (int*)carve(SZ_GO);

    f16* Wih = nullptr;
    f16* xh  = nullptr;
    if (off + SZ_WIH + 256 <= ws_size) Wih = (f16*)carve(SZ_WIH);
    if (Wih && off + SZ_XH + 256 <= ws_size) xh = (f16*)carve(SZ_XH);
    (void)in_sizes; (void)n_in; (void)out_size;

    hipMemsetAsync(arr, 0, SZ_ARR, stream);
    hipMemsetAsync(go, 0, SZ_GO, stream);

    if (xh)  k_f32_to_f16<<<2048, 256, 0, stream>>>(x,  xh,  (T_ * B_ * I_) / 8);
    if (Wih) k_f32_to_f16<<<2048, 256, 0, stream>>>(Wi, Wih, (E_ * G4 * I_) / 8);
    k_f32_to_f16<<<512,  256, 0, stream>>>(Wo, Woh, (E_ * C_ * H_) / 8);
    k_mix_biases<<<512, 256, 0, stream>>>(coef, bi, bh, bo, gbias, bom);
    k_init_h0h<<<(B_ * H_ + 255) / 256, 256, 0, stream>>>(h0, h0h);

    dim3 gx(32, 64);
    if (xh)
        k_xi_gemm<true,  true ><<<gx, 256, 0, stream>>>(xh, nullptr, Wih, nullptr, coef, gbias, xi);
    else if (Wih)
        k_xi_gemm<false, true ><<<gx, 256, 0, stream>>>(nullptr, x, Wih, nullptr, coef, gbias, xi);
    else
        k_xi_gemm<false, false><<<gx, 256, 0, stream>>>(nullptr, x, nullptr, Wi, coef, gbias, xi);

    // persistent recurrence: one cooperative launch, 256 blocks x 512 threads
    {
        void* args[] = { (void*)&Wh, (void*)&h0h, (void*)&c0, (void*)&xi,
                         (void*)&coef, (void*)&out, (void*)&arr, (void*)&go };
        hipLaunchCooperativeKernel((const void*)k_rec_persist, dim3(256), dim3(512),
                                   args, 0, stream);
    }

    dim3 go_(2, 256);
    k_out_gemm<<<go_, 256, 0, stream>>>(xi, Woh, coef, bom, out);
}

// Round 16
// 2316.364 us; speedup vs baseline: 1.1606x; 1.1606x over previous
//
#include <hip/hip_runtime.h>
#include <hip/hip_fp16.h>
#include <cstdint>

// Problem constants
#define T_  256
#define B_  64
#define I_  1024
#define H_  1024
#define E_  4
#define C_  128
#define G4  4096   // 4*H

typedef _Float16 f16;
typedef _Float16 f16x2 __attribute__((ext_vector_type(2)));
typedef _Float16 f16x8 __attribute__((ext_vector_type(8)));
typedef float    f32x4 __attribute__((ext_vector_type(4)));

__device__ __forceinline__ float sigmoidf_(float x) { return 1.f / (1.f + __expf(-x)); }

union pk2 { uint32_t u; f16x2 h; };

// ---------------- conversion f32 -> f16 (vectorized, grid-stride) -------------
__global__ void k_f32_to_f16(const float* __restrict__ src, f16* __restrict__ dst, int n8) {
    int i = blockIdx.x * blockDim.x + threadIdx.x;
    int stride = gridDim.x * blockDim.x;
    for (; i < n8; i += stride) {
        const float4* s = reinterpret_cast<const float4*>(src) + (size_t)i * 2;
        float4 a = s[0], b = s[1];
        f16x8 v = { (f16)a.x, (f16)a.y, (f16)a.z, (f16)a.w,
                    (f16)b.x, (f16)b.y, (f16)b.z, (f16)b.w };
        *reinterpret_cast<f16x8*>(dst + (size_t)i * 8) = v;
    }
}

// ---------------- mixed biases: gbias = coef@(bi+bh), bom = coef@bo ----------
__global__ void k_mix_biases(const float* __restrict__ coef, const float* __restrict__ bi,
                             const float* __restrict__ bh, const float* __restrict__ bo,
                             float* __restrict__ gbias, float* __restrict__ bom) {
    int idx = blockIdx.x * blockDim.x + threadIdx.x;
    int stride = gridDim.x * blockDim.x;
    for (int i = idx; i < B_ * G4; i += stride) {
        int b = i >> 12, o = i & (G4 - 1);
        float s = 0.f;
#pragma unroll
        for (int e = 0; e < 4; ++e) s += coef[b * 4 + e] * (bi[e * G4 + o] + bh[e * G4 + o]);
        gbias[i] = s;
    }
    for (int i = idx; i < B_ * C_; i += stride) {
        int b = i >> 7, c = i & (C_ - 1);
        float s = 0.f;
#pragma unroll
        for (int e = 0; e < 4; ++e) s += coef[b * 4 + e] * bo[e * C_ + c];
        bom[i] = s;
    }
}

// ---------------- h0 -> f16 --------------------------------------------------
__global__ void k_init_h0h(const float* __restrict__ h0, f16* __restrict__ h0h) {
    int i = blockIdx.x * blockDim.x + threadIdx.x;
    if (i < B_ * H_) h0h[i] = (f16)h0[i];
}

// ---------------- xi GEMM: per-sample mixed input projection -----------------
template<bool XF16, bool WF16>
__global__ __launch_bounds__(256, 1) void k_xi_gemm(
        const f16* __restrict__ xh, const float* __restrict__ xf,
        const f16* __restrict__ Wih, const float* __restrict__ Wif,
        const float* __restrict__ coef, const float* __restrict__ gbias,
        f16* __restrict__ xi) {
    __shared__ f16 As[256 * 72];
    __shared__ f16 Bs[128 * 72];
    const int nt = blockIdx.x;      // 0..31  (128-col tile of 4096)
    const int b  = blockIdx.y;      // 0..63
    const int tid = threadIdx.x;
    const int lane = tid & 63, wave = tid >> 6;
    const int wr = wave >> 1, wc = wave & 1;

    float cf[4];
#pragma unroll
    for (int e = 0; e < 4; ++e) cf[e] = coef[b * 4 + e];

    f32x4 acc[8][4];
#pragma unroll
    for (int mi = 0; mi < 8; ++mi)
#pragma unroll
        for (int ni = 0; ni < 4; ++ni) acc[mi][ni] = 0.f;

    for (int kk = 0; kk < I_; kk += 64) {
        __syncthreads();
#pragma unroll
        for (int it = 0; it < 8; ++it) {
            int chunk = it * 256 + tid;
            int row = chunk >> 3, c8 = chunk & 7;
            if constexpr (XF16) {
                *reinterpret_cast<f16x8*>(&As[row * 72 + c8 * 8]) =
                    *reinterpret_cast<const f16x8*>(&xh[((size_t)row * B_ + b) * I_ + kk + c8 * 8]);
            } else {
                const float4* p = reinterpret_cast<const float4*>(&xf[((size_t)row * B_ + b) * I_ + kk + c8 * 8]);
                float4 a = p[0], bq = p[1];
                f16x8 v = { (f16)a.x, (f16)a.y, (f16)a.z, (f16)a.w,
                            (f16)bq.x, (f16)bq.y, (f16)bq.z, (f16)bq.w };
                *reinterpret_cast<f16x8*>(&As[row * 72 + c8 * 8]) = v;
            }
        }
#pragma unroll
        for (int it = 0; it < 4; ++it) {
            int chunk = it * 256 + tid;
            int n = chunk >> 3, c8 = chunk & 7;
            if constexpr (WF16) {
                size_t base = ((size_t)(nt * 128 + n)) * I_ + kk + c8 * 8;
                f16 c0 = (f16)cf[0], c1 = (f16)cf[1], c2 = (f16)cf[2], c3 = (f16)cf[3];
                f16x8 w0 = *reinterpret_cast<const f16x8*>(&Wih[base]);
                f16x8 w1 = *reinterpret_cast<const f16x8*>(&Wih[base + (size_t)1 * G4 * I_]);
                f16x8 w2 = *reinterpret_cast<const f16x8*>(&Wih[base + (size_t)2 * G4 * I_]);
                f16x8 w3 = *reinterpret_cast<const f16x8*>(&Wih[base + (size_t)3 * G4 * I_]);
                f16x8 m = w0 * c0 + w1 * c1 + w2 * c2 + w3 * c3;
                *reinterpret_cast<f16x8*>(&Bs[n * 72 + c8 * 8]) = m;
            } else {
                size_t base = ((size_t)(nt * 128 + n)) * I_ + kk + c8 * 8;
                float m[8];
#pragma unroll
                for (int j = 0; j < 8; ++j) m[j] = 0.f;
#pragma unroll
                for (int e = 0; e < 4; ++e) {
                    const float4* p = reinterpret_cast<const float4*>(&Wif[base + (size_t)e * G4 * I_]);
                    float4 a = p[0], bq = p[1];
                    m[0] += cf[e] * a.x;  m[1] += cf[e] * a.y;
                    m[2] += cf[e] * a.z;  m[3] += cf[e] * a.w;
                    m[4] += cf[e] * bq.x; m[5] += cf[e] * bq.y;
                    m[6] += cf[e] * bq.z; m[7] += cf[e] * bq.w;
                }
                f16x8 v = { (f16)m[0], (f16)m[1], (f16)m[2], (f16)m[3],
                            (f16)m[4], (f16)m[5], (f16)m[6], (f16)m[7] };
                *reinterpret_cast<f16x8*>(&Bs[n * 72 + c8 * 8]) = v;
            }
        }
        __syncthreads();
#pragma unroll
        for (int ks = 0; ks < 2; ++ks) {
            int ko = ks * 32 + (lane >> 4) * 8;
            f16x8 a[8], bb[4];
#pragma unroll
            for (int mi = 0; mi < 8; ++mi)
                a[mi] = *reinterpret_cast<const f16x8*>(&As[(wr * 128 + mi * 16 + (lane & 15)) * 72 + ko]);
#pragma unroll
            for (int ni = 0; ni < 4; ++ni)
                bb[ni] = *reinterpret_cast<const f16x8*>(&Bs[(wc * 64 + ni * 16 + (lane & 15)) * 72 + ko]);
#pragma unroll
            for (int mi = 0; mi < 8; ++mi)
#pragma unroll
                for (int ni = 0; ni < 4; ++ni)
                    acc[mi][ni] = __builtin_amdgcn_mfma_f32_16x16x32_f16(a[mi], bb[ni], acc[mi][ni], 0, 0, 0);
        }
    }
#pragma unroll
    for (int mi = 0; mi < 8; ++mi)
#pragma unroll
        for (int ni = 0; ni < 4; ++ni)
#pragma unroll
            for (int j = 0; j < 4; ++j) {
                int t = wr * 128 + mi * 16 + (lane >> 4) * 4 + j;
                int o = nt * 128 + wc * 64 + ni * 16 + (lane & 15);
                float v = acc[mi][ni][j] + gbias[b * G4 + o];
                xi[((size_t)t * B_ + b) * G4 + o] = (f16)v;
            }
}

// ---------------- persistent recurrence: per-tile DATAFLOW sync --------------
// No global barrier. Producer jb, after step t: drain h stores (sync), set own
// arr[t][jb] (relaxed agent atomic), drain, then wave-0 threads 0..15 read the
// 16 arr slots of jb's tile group (one 64B line); if ALL set (the temporally
// last producer is guaranteed to see this, since its peer-loads issue after
// its own store reached the L3 serialization point), publish 16 fan-out
// go2[t][tile] lines. Consumers poll go2 per tile: tiles 0-7 at step start
// (threads 0-7, one 16-poller line each), tiles 8-11 / 12-15 mid-K-loop,
// hidden under compute; KSTP syncs order polls vs PRE loads. Blocks may skew;
// the h-dependency chain bounds skew so the xi gate-0 overlay audit holds
// (gate-0 reads are L2-bypassing atomics, h_prev tile addresses never cached
// before their write).
#define POOL_SZ  148480
#define AS0_OFF  131072
#define AS1_OFF  (131072 + 8192)
#define GL_OFF   131072

#define BF(KC, KS) (*reinterpret_cast<const f16x8*>(pool + wrow + (KC) * 128 + (((KS) * 64 + koff) ^ swz)))
#define PRE(KC, PF) PF = *reinterpret_cast<const f16x8*>(&hprev[(size_t)sr * hstr + (KC) * 64 + soct * 8]);
#define AFR(AOFF, AROW, KS) (*reinterpret_cast<const f16x8*>(pool + (AOFF) + (AROW) + (((KS) * 64 + koff) ^ swz)))

#define MM4(ROFF) \
    acc0 = __builtin_amdgcn_mfma_f32_16x16x32_f16(AFR(ROFF, arow0, 0), bq0, acc0, 0, 0, 0); \
    acc1 = __builtin_amdgcn_mfma_f32_16x16x32_f16(AFR(ROFF, arow1, 0), bq0, acc1, 0, 0, 0); \
    acc0 = __builtin_amdgcn_mfma_f32_16x16x32_f16(AFR(ROFF, arow0, 1), bq1, acc0, 0, 0, 0); \
    acc1 = __builtin_amdgcn_mfma_f32_16x16x32_f16(AFR(ROFF, arow1, 1), bq1, acc1, 0, 0, 0);

#define KSTP(KC, ROFF, WOFF, PFW, PFL) { \
    const f16x8 bq0 = BF(KC, 0), bq1 = BF(KC, 1); \
    PRE((KC) + 4, PFL); \
    MM4(ROFF); \
    *reinterpret_cast<f16x8*>(pool + (WOFF) + sdst) = PFW; \
    __syncthreads(); \
}
#define KST(KC, ROFF, WOFF, PFW) { \
    const f16x8 bq0 = BF(KC, 0), bq1 = BF(KC, 1); \
    MM4(ROFF); \
    *reinterpret_cast<f16x8*>(pool + (WOFF) + sdst) = PFW; \
    __syncthreads(); \
}

// go2 line index for (t, kc): 16 lines of 64B, consumer picks line bid&15
#define GO2IDX(T, KC, L) ((((size_t)(T) * 16 + (KC)) * 16 + (L)) * 16)

__device__ __forceinline__ void pollgo(const int* p) {
    while (__hip_atomic_load(p, __ATOMIC_RELAXED, __HIP_MEMORY_SCOPE_AGENT) == 0)
        __builtin_amdgcn_s_sleep(1);
}

__global__ __launch_bounds__(512, 1) void k_rec_persist(
        const float* __restrict__ Wh, const f16* __restrict__ h0h,
        const float* __restrict__ c0, f16* xi, const float* __restrict__ coef,
        float* __restrict__ out, int* __restrict__ arr, int* __restrict__ go2) {
    __shared__ __attribute__((aligned(16))) char pool[POOL_SZ];
    float* gl = reinterpret_cast<float*>(pool + GL_OFF);   // [4][64][17]

    const int bid = blockIdx.x;
    const int jb = ((bid & 7) << 5) | (bid >> 3);          // XCD-contiguous cols
    const int tid = threadIdx.x, lane = tid & 63, w = tid >> 6;
    const int ex = w & 3, mh = w >> 2;                    // expert, M-half
    const int l15 = lane & 15, hi8 = (lane >> 4) * 8;
    const int myTile = jb >> 4;                           // tile this block produces into
    const int goLine = bid & 15;

    // ---- one-time: Wh slice f32 -> f16 into swizzled LDS ----
    for (int i = tid; i < 8192; i += 512) {
        int r = i >> 7, oct = i & 127;                    // r = e*16+g*4+c
        int e = r >> 4, g = (r >> 2) & 3, c = r & 3;
        const float* src = &Wh[((size_t)e * G4 + g * H_ + jb * 4 + c) * H_ + oct * 8];
        float4 f0 = *reinterpret_cast<const float4*>(src);
        float4 f1 = *reinterpret_cast<const float4*>(src + 4);
        f16x8 v = { (f16)f0.x, (f16)f0.y, (f16)f0.z, (f16)f0.w,
                    (f16)f1.x, (f16)f1.y, (f16)f1.z, (f16)f1.w };
        int db = r * 2048 + ((oct * 16) ^ ((r & 7) << 4));
        *reinterpret_cast<f16x8*>(pool + db) = v;
    }

    // cell-update identity: 128 threads x 2 adjacent cols (4B-aligned pairs)
    const int bb = tid >> 1, pr = tid & 1;
    const int cp0 = jb * 4 + pr * 2;
    float c_reg0 = 0.f, c_reg1 = 0.f;
    float4 cf4 = {0.f, 0.f, 0.f, 0.f};
    if (tid < 128) {
        c_reg0 = c0[bb * H_ + cp0];
        c_reg1 = c0[bb * H_ + cp0 + 1];
        cf4 = *reinterpret_cast<const float4*>(&coef[bb * 4]);
    }

    // per-thread LDS bases; swizzle applied to FULL within-row offset at use
    const int swz   = (l15 & 7) << 4;
    const int koff  = hi8 * 2;
    const int wrow  = (ex * 16 + l15) * 2048;
    const int arow0 = (mh * 32 + l15) * 128;
    const int arow1 = arow0 + 16 * 128;
    const int sr = tid >> 3, soct = tid & 7;
    const int sdst = sr * 128 + ((soct * 16) ^ ((sr & 7) << 4));

    __syncthreads();

    // gate double-buffer: step-0 gates (gate0 via 4B agent atomic: overlay line)
    float xgc0a = 0.f, xgc0b = 0.f, xgc1a = 0.f, xgc1b = 0.f;
    float xgc2a = 0.f, xgc2b = 0.f, xgc3a = 0.f, xgc3b = 0.f;
    if (tid < 128) {
        const f16* xp = &xi[((size_t)0 * B_ + bb) * G4 + cp0];
        pk2 p0; p0.u = __hip_atomic_load(reinterpret_cast<const uint32_t*>(xp),
                                         __ATOMIC_RELAXED, __HIP_MEMORY_SCOPE_AGENT);
        xgc0a = (float)p0.h.x; xgc0b = (float)p0.h.y;
        f16x2 g1 = *reinterpret_cast<const f16x2*>(xp + H_);
        f16x2 g2 = *reinterpret_cast<const f16x2*>(xp + 2 * H_);
        f16x2 g3 = *reinterpret_cast<const f16x2*>(xp + 3 * H_);
        xgc1a = (float)g1.x; xgc1b = (float)g1.y;
        xgc2a = (float)g2.x; xgc2b = (float)g2.y;
        xgc3a = (float)g3.x; xgc3b = (float)g3.y;
    }

    for (int t = 0; t < T_; ++t) {
        const f16* hprev = (t == 0) ? h0h : (xi + (size_t)(t - 1) * B_ * G4);
        const size_t hstr = (t == 0) ? (size_t)H_ : (size_t)G4;

        // wait for tiles 0..7 of h[t-1] (threads 0..7 in parallel)
        if (t > 0) {
            if (tid < 8) pollgo(&go2[GO2IDX(t - 1, tid, goLine)]);
            __builtin_amdgcn_sched_barrier(0);
            __syncthreads();
        }

        // prologue: 4-deep prefetch of tiles 0..3
        f16x8 pfa, pfb, pfc, pfd;
        PRE(0, pfa) PRE(1, pfb) PRE(2, pfc) PRE(3, pfd)

        // prefetch NEXT step's gates (consumed at t+1)
        float xgn0a = 0.f, xgn0b = 0.f, xgn1a = 0.f, xgn1b = 0.f;
        float xgn2a = 0.f, xgn2b = 0.f, xgn3a = 0.f, xgn3b = 0.f;
        if (t + 1 < T_ && tid < 128) {
            const f16* xq = &xi[((size_t)(t + 1) * B_ + bb) * G4 + cp0];
            pk2 p0; p0.u = __hip_atomic_load(reinterpret_cast<const uint32_t*>(xq),
                                             __ATOMIC_RELAXED, __HIP_MEMORY_SCOPE_AGENT);
            xgn0a = (float)p0.h.x; xgn0b = (float)p0.h.y;
            f16x2 g1 = *reinterpret_cast<const f16x2*>(xq + H_);
            f16x2 g2 = *reinterpret_cast<const f16x2*>(xq + 2 * H_);
            f16x2 g3 = *reinterpret_cast<const f16x2*>(xq + 3 * H_);
            xgn1a = (float)g1.x; xgn1b = (float)g1.y;
            xgn2a = (float)g2.x; xgn2b = (float)g2.y;
            xgn3a = (float)g3.x; xgn3b = (float)g3.y;
        }

        *reinterpret_cast<f16x8*>(pool + AS0_OFF + sdst) = pfa;   // tile 0
        f32x4 acc0 = {0.f, 0.f, 0.f, 0.f}, acc1 = {0.f, 0.f, 0.f, 0.f};
        __syncthreads();

        // tiles 8..11 needed from KSTP(4); poll now, hidden under KSTP(0..3)
        if (t > 0 && tid < 4) pollgo(&go2[GO2IDX(t - 1, 8 + tid, goLine)]);
        KSTP(0,  AS0_OFF, AS1_OFF, pfb, pfa)
        KSTP(1,  AS1_OFF, AS0_OFF, pfc, pfb)
        KSTP(2,  AS0_OFF, AS1_OFF, pfd, pfc)
        KSTP(3,  AS1_OFF, AS0_OFF, pfa, pfd)
        // tiles 12..15 needed from KSTP(8); poll now, hidden under KSTP(4..7)
        if (t > 0 && tid < 4) pollgo(&go2[GO2IDX(t - 1, 12 + tid, goLine)]);
        KSTP(4,  AS0_OFF, AS1_OFF, pfb, pfa)
        KSTP(5,  AS1_OFF, AS0_OFF, pfc, pfb)
        KSTP(6,  AS0_OFF, AS1_OFF, pfd, pfc)
        KSTP(7,  AS1_OFF, AS0_OFF, pfa, pfd)
        KSTP(8,  AS0_OFF, AS1_OFF, pfb, pfa)
        KSTP(9,  AS1_OFF, AS0_OFF, pfc, pfb)
        KSTP(10, AS0_OFF, AS1_OFF, pfd, pfc)
        KSTP(11, AS1_OFF, AS0_OFF, pfa, pfd)
        KST(12,  AS0_OFF, AS1_OFF, pfb)
        KST(13,  AS1_OFF, AS0_OFF, pfc)
        KST(14,  AS0_OFF, AS1_OFF, pfd)
        // tile 15: MFMA only + trailing sync (gl overlay becomes safe)
        {
            const f16x8 bq0 = BF(15, 0), bq1 = BF(15, 1);
            MM4(AS1_OFF);
            __syncthreads();
        }

        // park per-expert partials into gl (overlays As0/As1)
#pragma unroll
        for (int j = 0; j < 4; ++j) {
            int r0 = mh * 32 + (lane >> 4) * 4 + j;
            gl[(ex * 64 + r0) * 17 + l15]      = acc0[j];
            gl[(ex * 64 + r0 + 16) * 17 + l15] = acc1[j];
        }
        __syncthreads();

        // mix experts + cell update (128 threads x 2 cols); 4B agent-atomic h store
        if (tid < 128) {
            float ga[4], gb[4];
#pragma unroll
            for (int g = 0; g < 4; ++g) {
                int nn = g * 4 + pr * 2;
                ga[g] = cf4.x * gl[(0 * 64 + bb) * 17 + nn] +
                        cf4.y * gl[(1 * 64 + bb) * 17 + nn] +
                        cf4.z * gl[(2 * 64 + bb) * 17 + nn] +
                        cf4.w * gl[(3 * 64 + bb) * 17 + nn];
                gb[g] = cf4.x * gl[(0 * 64 + bb) * 17 + nn + 1] +
                        cf4.y * gl[(1 * 64 + bb) * 17 + nn + 1] +
                        cf4.z * gl[(2 * 64 + bb) * 17 + nn + 1] +
                        cf4.w * gl[(3 * 64 + bb) * 17 + nn + 1];
            }
            ga[0] += xgc0a; ga[1] += xgc1a; ga[2] += xgc2a; ga[3] += xgc3a;
            gb[0] += xgc0b; gb[1] += xgc1b; gb[2] += xgc2b; gb[3] += xgc3b;
            float cn0 = sigmoidf_(ga[1]) * c_reg0 + sigmoidf_(ga[0]) * tanhf(ga[2]);
            float hn0 = sigmoidf_(ga[3]) * tanhf(cn0);
            float cn1 = sigmoidf_(gb[1]) * c_reg1 + sigmoidf_(gb[0]) * tanhf(gb[2]);
            float hn1 = sigmoidf_(gb[3]) * tanhf(cn1);
            c_reg0 = cn0; c_reg1 = cn1;
            pk2 st; st.h.x = (f16)hn0; st.h.y = (f16)hn1;
            __hip_atomic_store(reinterpret_cast<uint32_t*>(&xi[((size_t)t * B_ + bb) * G4 + cp0]),
                               st.u, __ATOMIC_RELAXED, __HIP_MEMORY_SCOPE_AGENT);
            if (t == T_ - 1) {
                out[(size_t)T_ * B_ * C_ + bb * H_ + cp0]     = hn0;
                out[(size_t)T_ * B_ * C_ + bb * H_ + cp0 + 1] = hn1;
                out[(size_t)T_ * B_ * C_ + B_ * H_ + bb * H_ + cp0]     = cn0;
                out[(size_t)T_ * B_ * C_ + B_ * H_ + bb * H_ + cp0 + 1] = cn1;
            }
        }
        xgc0a = xgn0a; xgc0b = xgn0b; xgc1a = xgn1a; xgc1b = xgn1b;
        xgc2a = xgn2a; xgc2b = xgn2b; xgc3a = xgn3a; xgc3b = xgn3b;

        // publish: arrival slot + (if group complete) per-tile go lines
        if (t < T_ - 1) {
            __syncthreads();   // drain h stores (vmcnt0)
            if (tid == 0)
                __hip_atomic_store(&arr[t * 256 + jb], 1, __ATOMIC_RELAXED,
                                   __HIP_MEMORY_SCOPE_AGENT);
            __syncthreads();   // drain arr store before peer loads
            if (tid < 64) {    // wave 0: check tile group (one 64B line), publish
                int v = 1;
                if (lane < 16)
                    v = __hip_atomic_load(&arr[t * 256 + myTile * 16 + lane],
                                          __ATOMIC_RELAXED, __HIP_MEMORY_SCOPE_AGENT);
                unsigned long long m = __ballot(v != 0);
                if (m == ~0ull && lane < 16)
                    __hip_atomic_store(&go2[GO2IDX(t, myTile, lane)], 1,
                                       __ATOMIC_RELAXED, __HIP_MEMORY_SCOPE_AGENT);
            }
        }
    }
}

// ---------------- output projection ------------------------------------------
__global__ __launch_bounds__(256, 1) void k_out_gemm(
        const f16* __restrict__ hs, const f16* __restrict__ Woh,
        const float* __restrict__ coef, const float* __restrict__ bom,
        float* __restrict__ out) {
    __shared__ f16 As[64 * 72];
    __shared__ f16 Bs[256 * 72];
    __shared__ float cfs[64][4];
    const int nt = blockIdx.x;   // 0..1
    const int t  = blockIdx.y;   // 0..255
    const int tid = threadIdx.x, lane = tid & 63, w = tid >> 6;
    cfs[tid >> 2][tid & 3] = coef[tid];

    f32x4 acc[4][4];
#pragma unroll
    for (int e = 0; e < 4; ++e)
#pragma unroll
        for (int mi = 0; mi < 4; ++mi) acc[e][mi] = 0.f;

    for (int kk = 0; kk < H_; kk += 64) {
        __syncthreads();
#pragma unroll
        for (int it = 0; it < 2; ++it) {   // A: hs[t] 64x64 (stride G4 overlay)
            int chunk = it * 256 + tid;
            int row = chunk >> 3, c8 = chunk & 7;
            *reinterpret_cast<f16x8*>(&As[row * 72 + c8 * 8]) =
                *reinterpret_cast<const f16x8*>(&hs[((size_t)t * B_ + row) * G4 + kk + c8 * 8]);
        }
#pragma unroll
        for (int it = 0; it < 8; ++it) {   // B: Wo rows e*C + nt*64 + n
            int chunk = it * 256 + tid;
            int r = chunk >> 3, c8 = chunk & 7;
            int e = r >> 6, nn = r & 63;
            size_t grow = (size_t)e * C_ + nt * 64 + nn;
            *reinterpret_cast<f16x8*>(&Bs[r * 72 + c8 * 8]) =
                *reinterpret_cast<const f16x8*>(&Woh[grow * H_ + kk + c8 * 8]);
        }
        __syncthreads();
#pragma unroll
        for (int ks = 0; ks < 2; ++ks) {
            int ko = ks * 32 + (lane >> 4) * 8;
            f16x8 a[4];
#pragma unroll
            for (int mi = 0; mi < 4; ++mi)
                a[mi] = *reinterpret_cast<const f16x8*>(&As[(mi * 16 + (lane & 15)) * 72 + ko]);
#pragma unroll
            for (int e = 0; e < 4; ++e) {
                f16x8 bf = *reinterpret_cast<const f16x8*>(&Bs[(e * 64 + w * 16 + (lane & 15)) * 72 + ko]);
#pragma unroll
                for (int mi = 0; mi < 4; ++mi)
                    acc[e][mi] = __builtin_amdgcn_mfma_f32_16x16x32_f16(a[mi], bf, acc[e][mi], 0, 0, 0);
            }
        }
    }
#pragma unroll
    for (int mi = 0; mi < 4; ++mi)
#pragma unroll
        for (int j = 0; j < 4; ++j) {
            int bb = mi * 16 + (lane >> 4) * 4 + j;
            int cc = nt * 64 + w * 16 + (lane & 15);
            float v = cfs[bb][0] * acc[0][mi][j] + cfs[bb][1] * acc[1][mi][j] +
                      cfs[bb][2] * acc[2][mi][j] + cfs[bb][3] * acc[3][mi][j];
            v += bom[bb * C_ + cc];
            out[((size_t)t * B_ + bb) * C_ + cc] = v;
        }
}

extern "C" void kernel_launch(void* const* d_in, const int* in_sizes, int n_in,
                              void* d_out, int out_size, void* d_ws, size_t ws_size,
                              hipStream_t stream) {
    const float* x    = (const float*)d_in[0];
    const float* h0   = (const float*)d_in[1];
    const float* c0   = (const float*)d_in[2];
    const float* coef = (const float*)d_in[3];
    const float* Wi   = (const float*)d_in[4];
    const float* bi   = (const float*)d_in[5];
    const float* Wh   = (const float*)d_in[6];
    const float* bh   = (const float*)d_in[7];
    const float* Wo   = (const float*)d_in[8];
    const float* bo   = (const float*)d_in[9];
    float* out = (float*)d_out;

    char* base = (char*)d_ws;
    size_t off = 0;
    auto carve = [&](size_t bytes) -> char* {
        char* r = base + off;
        off = (off + bytes + 255) & ~(size_t)255;
        return r;
    };
    const size_t SZ_XI  = (size_t)T_ * B_ * G4 * 2;       // 134.2 MB (gate-0 = hs)
    const size_t SZ_WOH = (size_t)E_ * C_ * H_ * 2;       // 1 MB
    const size_t SZ_ARR = (size_t)T_ * 256 * 4;           // arrival slots (256 KB)
    const size_t SZ_GO2 = (size_t)T_ * 16 * 16 * 16 * 4;  // per-tile go lines (4 MB)
    const size_t SZ_WIH = (size_t)E_ * G4 * I_ * 2;       // 33.5 MB (optional)
    const size_t SZ_XH  = (size_t)T_ * B_ * I_ * 2;       // 33.5 MB (optional)

    f16*   xi     = (f16*)carve(SZ_XI);
    f16*   Woh    = (f16*)carve(SZ_WOH);
    f16*   h0h    = (f16*)carve((size_t)B_ * H_ * 2);
    float* gbias  = (float*)carve((size_t)B_ * G4 * 4);
    float* bom    = (float*)carve((size_t)B_ * C_ * 4);
    int*   arr    = (int*)carve(SZ_ARR);
    int*   go2    = (int*)carve(SZ_GO2);

    f16* Wih = nullptr;
    f16* xh  = nullptr;
    if (off + SZ_WIH + 256 <= ws_size) Wih = (f16*)carve(SZ_WIH);
    if (Wih && off + SZ_XH + 256 <= ws_size) xh = (f16*)carve(SZ_XH);
    (void)in_sizes; (void)n_in; (void)out_size;

    hipMemsetAsync(arr, 0, SZ_ARR, stream);
    hipMemsetAsync(go2, 0, SZ_GO2, stream);

    if (xh)  k_f32_to_f16<<<2048, 256, 0, stream>>>(x,  xh,  (T_ * B_ * I_) / 8);
    if (Wih) k_f32_to_f16<<<2048, 256, 0, stream>>>(Wi, Wih, (E_ * G4 * I_) / 8);
    k_f32_to_f16<<<512,  256, 0, stream>>>(Wo, Woh, (E_ * C_ * H_) / 8);
    k_mix_biases<<<512, 256, 0, stream>>>(coef, bi, bh, bo, gbias, bom);
    k_init_h0h<<<(B_ * H_ + 255) / 256, 256, 0, stream>>>(h0, h0h);

    dim3 gx(32, 64);
    if (xh)
        k_xi_gemm<true,  true ><<<gx, 256, 0, stream>>>(xh, nullptr, Wih, nullptr, coef, gbias, xi);
    else if (Wih)
        k_xi_gemm<false, true ><<<gx, 256, 0, stream>>>(nullptr, x, Wih, nullptr, coef, gbias, xi);
    else
        k_xi_gemm<false, false><<<gx, 256, 0, stream>>>(nullptr, x, nullptr, Wi, coef, gbias, xi);

    // persistent recurrence: one cooperative launch, 256 blocks x 512 threads
    {
        void* args[] = { (void*)&Wh, (void*)&h0h, (void*)&c0, (void*)&xi,
                         (void*)&coef, (void*)&out, (void*)&arr, (void*)&go2 };
        hipLaunchCooperativeKernel((const void*)k_rec_persist, dim3(256), dim3(512),
                                   args, 0, stream);
    }

    dim3 go_(2, 256);
    k_out_gemm<<<go_, 256, 0, stream>>>(xi, Woh, coef, bom, out);
}

// Round 17
// 2256.878 us; speedup vs baseline: 1.1912x; 1.0264x over previous
//
#include <hip/hip_runtime.h>
#include <hip/hip_fp16.h>
#include <cstdint>

// Problem constants
#define T_  256
#define B_  64
#define I_  1024
#define H_  1024
#define E_  4
#define C_  128
#define G4  4096   // 4*H

typedef _Float16 f16;
typedef _Float16 f16x2 __attribute__((ext_vector_type(2)));
typedef _Float16 f16x8 __attribute__((ext_vector_type(8)));
typedef float    f32x4 __attribute__((ext_vector_type(4)));

__device__ __forceinline__ float sigmoidf_(float x) { return 1.f / (1.f + __expf(-x)); }

union pk2 { uint32_t u; f16x2 h; };

// ---------------- conversion f32 -> f16 (vectorized, grid-stride) -------------
__global__ void k_f32_to_f16(const float* __restrict__ src, f16* __restrict__ dst, int n8) {
    int i = blockIdx.x * blockDim.x + threadIdx.x;
    int stride = gridDim.x * blockDim.x;
    for (; i < n8; i += stride) {
        const float4* s = reinterpret_cast<const float4*>(src) + (size_t)i * 2;
        float4 a = s[0], b = s[1];
        f16x8 v = { (f16)a.x, (f16)a.y, (f16)a.z, (f16)a.w,
                    (f16)b.x, (f16)b.y, (f16)b.z, (f16)b.w };
        *reinterpret_cast<f16x8*>(dst + (size_t)i * 8) = v;
    }
}

// ---------------- mixed biases: gbias = coef@(bi+bh), bom = coef@bo ----------
__global__ void k_mix_biases(const float* __restrict__ coef, const float* __restrict__ bi,
                             const float* __restrict__ bh, const float* __restrict__ bo,
                             float* __restrict__ gbias, float* __restrict__ bom) {
    int idx = blockIdx.x * blockDim.x + threadIdx.x;
    int stride = gridDim.x * blockDim.x;
    for (int i = idx; i < B_ * G4; i += stride) {
        int b = i >> 12, o = i & (G4 - 1);
        float s = 0.f;
#pragma unroll
        for (int e = 0; e < 4; ++e) s += coef[b * 4 + e] * (bi[e * G4 + o] + bh[e * G4 + o]);
        gbias[i] = s;
    }
    for (int i = idx; i < B_ * C_; i += stride) {
        int b = i >> 7, c = i & (C_ - 1);
        float s = 0.f;
#pragma unroll
        for (int e = 0; e < 4; ++e) s += coef[b * 4 + e] * bo[e * C_ + c];
        bom[i] = s;
    }
}

// ---------------- h0 -> f16 --------------------------------------------------
__global__ void k_init_h0h(const float* __restrict__ h0, f16* __restrict__ h0h) {
    int i = blockIdx.x * blockDim.x + threadIdx.x;
    if (i < B_ * H_) h0h[i] = (f16)h0[i];
}

// ---------------- xi GEMM: per-sample mixed input projection -----------------
template<bool XF16, bool WF16>
__global__ __launch_bounds__(256, 1) void k_xi_gemm(
        const f16* __restrict__ xh, const float* __restrict__ xf,
        const f16* __restrict__ Wih, const float* __restrict__ Wif,
        const float* __restrict__ coef, const float* __restrict__ gbias,
        f16* __restrict__ xi) {
    __shared__ f16 As[256 * 72];
    __shared__ f16 Bs[128 * 72];
    const int nt = blockIdx.x;      // 0..31  (128-col tile of 4096)
    const int b  = blockIdx.y;      // 0..63
    const int tid = threadIdx.x;
    const int lane = tid & 63, wave = tid >> 6;
    const int wr = wave >> 1, wc = wave & 1;

    float cf[4];
#pragma unroll
    for (int e = 0; e < 4; ++e) cf[e] = coef[b * 4 + e];

    f32x4 acc[8][4];
#pragma unroll
    for (int mi = 0; mi < 8; ++mi)
#pragma unroll
        for (int ni = 0; ni < 4; ++ni) acc[mi][ni] = 0.f;

    for (int kk = 0; kk < I_; kk += 64) {
        __syncthreads();
#pragma unroll
        for (int it = 0; it < 8; ++it) {
            int chunk = it * 256 + tid;
            int row = chunk >> 3, c8 = chunk & 7;
            if constexpr (XF16) {
                *reinterpret_cast<f16x8*>(&As[row * 72 + c8 * 8]) =
                    *reinterpret_cast<const f16x8*>(&xh[((size_t)row * B_ + b) * I_ + kk + c8 * 8]);
            } else {
                const float4* p = reinterpret_cast<const float4*>(&xf[((size_t)row * B_ + b) * I_ + kk + c8 * 8]);
                float4 a = p[0], bq = p[1];
                f16x8 v = { (f16)a.x, (f16)a.y, (f16)a.z, (f16)a.w,
                            (f16)bq.x, (f16)bq.y, (f16)bq.z, (f16)bq.w };
                *reinterpret_cast<f16x8*>(&As[row * 72 + c8 * 8]) = v;
            }
        }
#pragma unroll
        for (int it = 0; it < 4; ++it) {
            int chunk = it * 256 + tid;
            int n = chunk >> 3, c8 = chunk & 7;
            if constexpr (WF16) {
                size_t base = ((size_t)(nt * 128 + n)) * I_ + kk + c8 * 8;
                f16 c0 = (f16)cf[0], c1 = (f16)cf[1], c2 = (f16)cf[2], c3 = (f16)cf[3];
                f16x8 w0 = *reinterpret_cast<const f16x8*>(&Wih[base]);
                f16x8 w1 = *reinterpret_cast<const f16x8*>(&Wih[base + (size_t)1 * G4 * I_]);
                f16x8 w2 = *reinterpret_cast<const f16x8*>(&Wih[base + (size_t)2 * G4 * I_]);
                f16x8 w3 = *reinterpret_cast<const f16x8*>(&Wih[base + (size_t)3 * G4 * I_]);
                f16x8 m = w0 * c0 + w1 * c1 + w2 * c2 + w3 * c3;
                *reinterpret_cast<f16x8*>(&Bs[n * 72 + c8 * 8]) = m;
            } else {
                size_t base = ((size_t)(nt * 128 + n)) * I_ + kk + c8 * 8;
                float m[8];
#pragma unroll
                for (int j = 0; j < 8; ++j) m[j] = 0.f;
#pragma unroll
                for (int e = 0; e < 4; ++e) {
                    const float4* p = reinterpret_cast<const float4*>(&Wif[base + (size_t)e * G4 * I_]);
                    float4 a = p[0], bq = p[1];
                    m[0] += cf[e] * a.x;  m[1] += cf[e] * a.y;
                    m[2] += cf[e] * a.z;  m[3] += cf[e] * a.w;
                    m[4] += cf[e] * bq.x; m[5] += cf[e] * bq.y;
                    m[6] += cf[e] * bq.z; m[7] += cf[e] * bq.w;
                }
                f16x8 v = { (f16)m[0], (f16)m[1], (f16)m[2], (f16)m[3],
                            (f16)m[4], (f16)m[5], (f16)m[6], (f16)m[7] };
                *reinterpret_cast<f16x8*>(&Bs[n * 72 + c8 * 8]) = v;
            }
        }
        __syncthreads();
#pragma unroll
        for (int ks = 0; ks < 2; ++ks) {
            int ko = ks * 32 + (lane >> 4) * 8;
            f16x8 a[8], bb[4];
#pragma unroll
            for (int mi = 0; mi < 8; ++mi)
                a[mi] = *reinterpret_cast<const f16x8*>(&As[(wr * 128 + mi * 16 + (lane & 15)) * 72 + ko]);
#pragma unroll
            for (int ni = 0; ni < 4; ++ni)
                bb[ni] = *reinterpret_cast<const f16x8*>(&Bs[(wc * 64 + ni * 16 + (lane & 15)) * 72 + ko]);
#pragma unroll
            for (int mi = 0; mi < 8; ++mi)
#pragma unroll
                for (int ni = 0; ni < 4; ++ni)
                    acc[mi][ni] = __builtin_amdgcn_mfma_f32_16x16x32_f16(a[mi], bb[ni], acc[mi][ni], 0, 0, 0);
        }
    }
#pragma unroll
    for (int mi = 0; mi < 8; ++mi)
#pragma unroll
        for (int ni = 0; ni < 4; ++ni)
#pragma unroll
            for (int j = 0; j < 4; ++j) {
                int t = wr * 128 + mi * 16 + (lane >> 4) * 4 + j;
                int o = nt * 128 + wc * 64 + ni * 16 + (lane & 15);
                float v = acc[mi][ni][j] + gbias[b * G4 + o];
                xi[((size_t)t * B_ + b) * G4 + o] = (f16)v;
            }
}

// ---------------- persistent recurrence: per-tile DATAFLOW sync (R16) --------
// + R17 delta: 4-buffer A rotation -> K-loop __syncthreads every OTHER tile
// (7 instead of 16). Tile k reads buf k%4, writes tile k+2 into buf (k+2)%4;
// RAW (write@k -> read@k+2) and WAR (read@k -> write@k+2) both cross the sync
// after tile k+1. LDS = W 131072 + 4*8192 = 163840 (exact CU limit); gl
// overlays the A region (dead after trailing sync).
#define POOL_SZ  163840
#define A0_OFF   131072
#define A1_OFF   (131072 + 8192)
#define A2_OFF   (131072 + 16384)
#define A3_OFF   (131072 + 24576)
#define GL_OFF   131072

#define BF(KC, KS) (*reinterpret_cast<const f16x8*>(pool + wrow + (KC) * 128 + (((KS) * 64 + koff) ^ swz)))
#define PRE(KC, PF) PF = *reinterpret_cast<const f16x8*>(&hprev[(size_t)sr * hstr + (KC) * 64 + soct * 8]);
#define AFR(AOFF, AROW, KS) (*reinterpret_cast<const f16x8*>(pool + (AOFF) + (AROW) + (((KS) * 64 + koff) ^ swz)))
#define WRA(AOFF, PF) *reinterpret_cast<f16x8*>(pool + (AOFF) + sdst) = PF;

#define MM4(ROFF, BQ0, BQ1) \
    acc0 = __builtin_amdgcn_mfma_f32_16x16x32_f16(AFR(ROFF, arow0, 0), BQ0, acc0, 0, 0, 0); \
    acc1 = __builtin_amdgcn_mfma_f32_16x16x32_f16(AFR(ROFF, arow1, 0), BQ0, acc1, 0, 0, 0); \
    acc0 = __builtin_amdgcn_mfma_f32_16x16x32_f16(AFR(ROFF, arow0, 1), BQ1, acc0, 0, 0, 0); \
    acc1 = __builtin_amdgcn_mfma_f32_16x16x32_f16(AFR(ROFF, arow1, 1), BQ1, acc1, 0, 0, 0);

// tile with PRE + write:   read RB, prefetch PK->PL, write PW->WB
#define TPW(KC, RB, PK, PL, PW, WB) { \
    const f16x8 bq0 = BF(KC, 0), bq1 = BF(KC, 1); \
    PRE(PK, PL); \
    MM4(RB, bq0, bq1); \
    WRA(WB, PW); \
}
// tile with write only
#define TW(KC, RB, PW, WB) { \
    const f16x8 bq0 = BF(KC, 0), bq1 = BF(KC, 1); \
    MM4(RB, bq0, bq1); \
    WRA(WB, PW); \
}
// tile, compute only
#define TN(KC, RB) { \
    const f16x8 bq0 = BF(KC, 0), bq1 = BF(KC, 1); \
    MM4(RB, bq0, bq1); \
}

// go2 line index for (t, kc): 16 lines of 64B, consumer picks line bid&15
#define GO2IDX(T, KC, L) ((((size_t)(T) * 16 + (KC)) * 16 + (L)) * 16)

__device__ __forceinline__ void pollgo(const int* p) {
    while (__hip_atomic_load(p, __ATOMIC_RELAXED, __HIP_MEMORY_SCOPE_AGENT) == 0)
        __builtin_amdgcn_s_sleep(1);
}

__global__ __launch_bounds__(512, 1) void k_rec_persist(
        const float* __restrict__ Wh, const f16* __restrict__ h0h,
        const float* __restrict__ c0, f16* xi, const float* __restrict__ coef,
        float* __restrict__ out, int* __restrict__ arr, int* __restrict__ go2) {
    __shared__ __attribute__((aligned(16))) char pool[POOL_SZ];
    float* gl = reinterpret_cast<float*>(pool + GL_OFF);   // [4][64][17]

    const int bid = blockIdx.x;
    const int jb = ((bid & 7) << 5) | (bid >> 3);          // XCD-contiguous cols
    const int tid = threadIdx.x, lane = tid & 63, w = tid >> 6;
    const int ex = w & 3, mh = w >> 2;                    // expert, M-half
    const int l15 = lane & 15, hi8 = (lane >> 4) * 8;
    const int myTile = jb >> 4;                           // tile this block produces into
    const int goLine = bid & 15;

    // ---- one-time: Wh slice f32 -> f16 into swizzled LDS ----
    for (int i = tid; i < 8192; i += 512) {
        int r = i >> 7, oct = i & 127;                    // r = e*16+g*4+c
        int e = r >> 4, g = (r >> 2) & 3, c = r & 3;
        const float* src = &Wh[((size_t)e * G4 + g * H_ + jb * 4 + c) * H_ + oct * 8];
        float4 f0 = *reinterpret_cast<const float4*>(src);
        float4 f1 = *reinterpret_cast<const float4*>(src + 4);
        f16x8 v = { (f16)f0.x, (f16)f0.y, (f16)f0.z, (f16)f0.w,
                    (f16)f1.x, (f16)f1.y, (f16)f1.z, (f16)f1.w };
        int db = r * 2048 + ((oct * 16) ^ ((r & 7) << 4));
        *reinterpret_cast<f16x8*>(pool + db) = v;
    }

    // cell-update identity: 128 threads x 2 adjacent cols (4B-aligned pairs)
    const int bb = tid >> 1, pr = tid & 1;
    const int cp0 = jb * 4 + pr * 2;
    float c_reg0 = 0.f, c_reg1 = 0.f;
    float4 cf4 = {0.f, 0.f, 0.f, 0.f};
    if (tid < 128) {
        c_reg0 = c0[bb * H_ + cp0];
        c_reg1 = c0[bb * H_ + cp0 + 1];
        cf4 = *reinterpret_cast<const float4*>(&coef[bb * 4]);
    }

    // per-thread LDS bases; swizzle applied to FULL within-row offset at use
    const int swz   = (l15 & 7) << 4;
    const int koff  = hi8 * 2;
    const int wrow  = (ex * 16 + l15) * 2048;
    const int arow0 = (mh * 32 + l15) * 128;
    const int arow1 = arow0 + 16 * 128;
    const int sr = tid >> 3, soct = tid & 7;
    const int sdst = sr * 128 + ((soct * 16) ^ ((sr & 7) << 4));

    __syncthreads();

    // gate double-buffer: step-0 gates (gate0 via 4B agent atomic: overlay line)
    float xgc0a = 0.f, xgc0b = 0.f, xgc1a = 0.f, xgc1b = 0.f;
    float xgc2a = 0.f, xgc2b = 0.f, xgc3a = 0.f, xgc3b = 0.f;
    if (tid < 128) {
        const f16* xp = &xi[((size_t)0 * B_ + bb) * G4 + cp0];
        pk2 p0; p0.u = __hip_atomic_load(reinterpret_cast<const uint32_t*>(xp),
                                         __ATOMIC_RELAXED, __HIP_MEMORY_SCOPE_AGENT);
        xgc0a = (float)p0.h.x; xgc0b = (float)p0.h.y;
        f16x2 g1 = *reinterpret_cast<const f16x2*>(xp + H_);
        f16x2 g2 = *reinterpret_cast<const f16x2*>(xp + 2 * H_);
        f16x2 g3 = *reinterpret_cast<const f16x2*>(xp + 3 * H_);
        xgc1a = (float)g1.x; xgc1b = (float)g1.y;
        xgc2a = (float)g2.x; xgc2b = (float)g2.y;
        xgc3a = (float)g3.x; xgc3b = (float)g3.y;
    }

    for (int t = 0; t < T_; ++t) {
        const f16* hprev = (t == 0) ? h0h : (xi + (size_t)(t - 1) * B_ * G4);
        const size_t hstr = (t == 0) ? (size_t)H_ : (size_t)G4;

        // wait for tiles 0..7 of h[t-1] (threads 0..7 in parallel)
        if (t > 0) {
            if (tid < 8) pollgo(&go2[GO2IDX(t - 1, tid, goLine)]);
            __builtin_amdgcn_sched_barrier(0);
            __syncthreads();
        }

        // prologue: 4-deep prefetch of tiles 0..3; write tiles 0,1
        f16x8 pfa, pfb, pfc, pfd;
        PRE(0, pfa) PRE(1, pfb) PRE(2, pfc) PRE(3, pfd)

        // prefetch NEXT step's gates (consumed at t+1)
        float xgn0a = 0.f, xgn0b = 0.f, xgn1a = 0.f, xgn1b = 0.f;
        float xgn2a = 0.f, xgn2b = 0.f, xgn3a = 0.f, xgn3b = 0.f;
        if (t + 1 < T_ && tid < 128) {
            const f16* xq = &xi[((size_t)(t + 1) * B_ + bb) * G4 + cp0];
            pk2 p0; p0.u = __hip_atomic_load(reinterpret_cast<const uint32_t*>(xq),
                                             __ATOMIC_RELAXED, __HIP_MEMORY_SCOPE_AGENT);
            xgn0a = (float)p0.h.x; xgn0b = (float)p0.h.y;
            f16x2 g1 = *reinterpret_cast<const f16x2*>(xq + H_);
            f16x2 g2 = *reinterpret_cast<const f16x2*>(xq + 2 * H_);
            f16x2 g3 = *reinterpret_cast<const f16x2*>(xq + 3 * H_);
            xgn1a = (float)g1.x; xgn1b = (float)g1.y;
            xgn2a = (float)g2.x; xgn2b = (float)g2.y;
            xgn3a = (float)g3.x; xgn3b = (float)g3.y;
        }

        WRA(A0_OFF, pfa)
        WRA(A1_OFF, pfb)
        f32x4 acc0 = {0.f, 0.f, 0.f, 0.f}, acc1 = {0.f, 0.f, 0.f, 0.f};
        __syncthreads();

        // tiles 8..11 first PREd at T4; poll now (covered by sync after T1)
        if (t > 0 && tid < 4) pollgo(&go2[GO2IDX(t - 1, 8 + tid, goLine)]);
        TPW(0, A0_OFF, 4, pfa, pfc, A2_OFF)
        TPW(1, A1_OFF, 5, pfb, pfd, A3_OFF)
        __syncthreads();
        TPW(2, A2_OFF, 6, pfc, pfa, A0_OFF)
        TPW(3, A3_OFF, 7, pfd, pfb, A1_OFF)
        __syncthreads();
        // tiles 12..15 first PREd at T8; poll now (covered by sync after T5)
        if (t > 0 && tid < 4) pollgo(&go2[GO2IDX(t - 1, 12 + tid, goLine)]);
        TPW(4, A0_OFF, 8, pfa, pfc, A2_OFF)
        TPW(5, A1_OFF, 9, pfb, pfd, A3_OFF)
        __syncthreads();
        TPW(6, A2_OFF, 10, pfc, pfa, A0_OFF)
        TPW(7, A3_OFF, 11, pfd, pfb, A1_OFF)
        __syncthreads();
        TPW(8, A0_OFF, 12, pfa, pfc, A2_OFF)
        TPW(9, A1_OFF, 13, pfb, pfd, A3_OFF)
        __syncthreads();
        TPW(10, A2_OFF, 14, pfc, pfa, A0_OFF)
        TPW(11, A3_OFF, 15, pfd, pfb, A1_OFF)
        __syncthreads();
        TW(12, A0_OFF, pfc, A2_OFF)
        TW(13, A1_OFF, pfd, A3_OFF)
        __syncthreads();
        TN(14, A2_OFF)
        TN(15, A3_OFF)
        __syncthreads();   // all A reads done -> gl overlay safe

        // park per-expert partials into gl (overlays A buffers)
#pragma unroll
        for (int j = 0; j < 4; ++j) {
            int r0 = mh * 32 + (lane >> 4) * 4 + j;
            gl[(ex * 64 + r0) * 17 + l15]      = acc0[j];
            gl[(ex * 64 + r0 + 16) * 17 + l15] = acc1[j];
        }
        __syncthreads();

        // mix experts + cell update (128 threads x 2 cols); 4B agent-atomic h store
        if (tid < 128) {
            float ga[4], gb[4];
#pragma unroll
            for (int g = 0; g < 4; ++g) {
                int nn = g * 4 + pr * 2;
                ga[g] = cf4.x * gl[(0 * 64 + bb) * 17 + nn] +
                        cf4.y * gl[(1 * 64 + bb) * 17 + nn] +
                        cf4.z * gl[(2 * 64 + bb) * 17 + nn] +
                        cf4.w * gl[(3 * 64 + bb) * 17 + nn];
                gb[g] = cf4.x * gl[(0 * 64 + bb) * 17 + nn + 1] +
                        cf4.y * gl[(1 * 64 + bb) * 17 + nn + 1] +
                        cf4.z * gl[(2 * 64 + bb) * 17 + nn + 1] +
                        cf4.w * gl[(3 * 64 + bb) * 17 + nn + 1];
            }
            ga[0] += xgc0a; ga[1] += xgc1a; ga[2] += xgc2a; ga[3] += xgc3a;
            gb[0] += xgc0b; gb[1] += xgc1b; gb[2] += xgc2b; gb[3] += xgc3b;
            float cn0 = sigmoidf_(ga[1]) * c_reg0 + sigmoidf_(ga[0]) * tanhf(ga[2]);
            float hn0 = sigmoidf_(ga[3]) * tanhf(cn0);
            float cn1 = sigmoidf_(gb[1]) * c_reg1 + sigmoidf_(gb[0]) * tanhf(gb[2]);
            float hn1 = sigmoidf_(gb[3]) * tanhf(cn1);
            c_reg0 = cn0; c_reg1 = cn1;
            pk2 st; st.h.x = (f16)hn0; st.h.y = (f16)hn1;
            __hip_atomic_store(reinterpret_cast<uint32_t*>(&xi[((size_t)t * B_ + bb) * G4 + cp0]),
                               st.u, __ATOMIC_RELAXED, __HIP_MEMORY_SCOPE_AGENT);
            if (t == T_ - 1) {
                out[(size_t)T_ * B_ * C_ + bb * H_ + cp0]     = hn0;
                out[(size_t)T_ * B_ * C_ + bb * H_ + cp0 + 1] = hn1;
                out[(size_t)T_ * B_ * C_ + B_ * H_ + bb * H_ + cp0]     = cn0;
                out[(size_t)T_ * B_ * C_ + B_ * H_ + bb * H_ + cp0 + 1] = cn1;
            }
        }
        xgc0a = xgn0a; xgc0b = xgn0b; xgc1a = xgn1a; xgc1b = xgn1b;
        xgc2a = xgn2a; xgc2b = xgn2b; xgc3a = xgn3a; xgc3b = xgn3b;

        // publish: arrival slot + (if group complete) per-tile go lines
        if (t < T_ - 1) {
            __syncthreads();   // drain h stores
            if (tid == 0)
                __hip_atomic_store(&arr[t * 256 + jb], 1, __ATOMIC_RELAXED,
                                   __HIP_MEMORY_SCOPE_AGENT);
            __syncthreads();   // drain arr store before peer loads
            if (tid < 64) {    // wave 0: check tile group (one 64B line), publish
                int v = 1;
                if (lane < 16)
                    v = __hip_atomic_load(&arr[t * 256 + myTile * 16 + lane],
                                          __ATOMIC_RELAXED, __HIP_MEMORY_SCOPE_AGENT);
                unsigned long long m = __ballot(v != 0);
                if (m == ~0ull && lane < 16)
                    __hip_atomic_store(&go2[GO2IDX(t, myTile, lane)], 1,
                                       __ATOMIC_RELAXED, __HIP_MEMORY_SCOPE_AGENT);
            }
        }
    }
}

// ---------------- output projection ------------------------------------------
__global__ __launch_bounds__(256, 1) void k_out_gemm(
        const f16* __restrict__ hs, const f16* __restrict__ Woh,
        const float* __restrict__ coef, const float* __restrict__ bom,
        float* __restrict__ out) {
    __shared__ f16 As[64 * 72];
    __shared__ f16 Bs[256 * 72];
    __shared__ float cfs[64][4];
    const int nt = blockIdx.x;   // 0..1
    const int t  = blockIdx.y;   // 0..255
    const int tid = threadIdx.x, lane = tid & 63, w = tid >> 6;
    cfs[tid >> 2][tid & 3] = coef[tid];

    f32x4 acc[4][4];
#pragma unroll
    for (int e = 0; e < 4; ++e)
#pragma unroll
        for (int mi = 0; mi < 4; ++mi) acc[e][mi] = 0.f;

    for (int kk = 0; kk < H_; kk += 64) {
        __syncthreads();
#pragma unroll
        for (int it = 0; it < 2; ++it) {   // A: hs[t] 64x64 (stride G4 overlay)
            int chunk = it * 256 + tid;
            int row = chunk >> 3, c8 = chunk & 7;
            *reinterpret_cast<f16x8*>(&As[row * 72 + c8 * 8]) =
                *reinterpret_cast<const f16x8*>(&hs[((size_t)t * B_ + row) * G4 + kk + c8 * 8]);
        }
#pragma unroll
        for (int it = 0; it < 8; ++it) {   // B: Wo rows e*C + nt*64 + n
            int chunk = it * 256 + tid;
            int r = chunk >> 3, c8 = chunk & 7;
            int e = r >> 6, nn = r & 63;
            size_t grow = (size_t)e * C_ + nt * 64 + nn;
            *reinterpret_cast<f16x8*>(&Bs[r * 72 + c8 * 8]) =
                *reinterpret_cast<const f16x8*>(&Woh[grow * H_ + kk + c8 * 8]);
        }
        __syncthreads();
#pragma unroll
        for (int ks = 0; ks < 2; ++ks) {
            int ko = ks * 32 + (lane >> 4) * 8;
            f16x8 a[4];
#pragma unroll
            for (int mi = 0; mi < 4; ++mi)
                a[mi] = *reinterpret_cast<const f16x8*>(&As[(mi * 16 + (lane & 15)) * 72 + ko]);
#pragma unroll
            for (int e = 0; e < 4; ++e) {
                f16x8 bf = *reinterpret_cast<const f16x8*>(&Bs[(e * 64 + w * 16 + (lane & 15)) * 72 + ko]);
#pragma unroll
                for (int mi = 0; mi < 4; ++mi)
                    acc[e][mi] = __builtin_amdgcn_mfma_f32_16x16x32_f16(a[mi], bf, acc[e][mi], 0, 0, 0);
            }
        }
    }
#pragma unroll
    for (int mi = 0; mi < 4; ++mi)
#pragma unroll
        for (int j = 0; j < 4; ++j) {
            int bb = mi * 16 + (lane >> 4) * 4 + j;
            int cc = nt * 64 + w * 16 + (lane & 15);
            float v = cfs[bb][0] * acc[0][mi][j] + cfs[bb][1] * acc[1][mi][j] +
                      cfs[bb][2] * acc[2][mi][j] + cfs[bb][3] * acc[3][mi][j];
            v += bom[bb * C_ + cc];
            out[((size_t)t * B_ + bb) * C_ + cc] = v;
        }
}

extern "C" void kernel_launch(void* const* d_in, const int* in_sizes, int n_in,
                              void* d_out, int out_size, void* d_ws, size_t ws_size,
                              hipStream_t stream) {
    const float* x    = (const float*)d_in[0];
    const float* h0   = (const float*)d_in[1];
    const float* c0   = (const float*)d_in[2];
    const float* coef = (const float*)d_in[3];
    const float* Wi   = (const float*)d_in[4];
    const float* bi   = (const float*)d_in[5];
    const float* Wh   = (const float*)d_in[6];
    const float* bh   = (const float*)d_in[7];
    const float* Wo   = (const float*)d_in[8];
    const float* bo   = (const float*)d_in[9];
    float* out = (float*)d_out;

    char* base = (char*)d_ws;
    size_t off = 0;
    auto carve = [&](size_t bytes) -> char* {
        char* r = base + off;
        off = (off + bytes + 255) & ~(size_t)255;
        return r;
    };
    const size_t SZ_XI  = (size_t)T_ * B_ * G4 * 2;       // 134.2 MB (gate-0 = hs)
    const size_t SZ_WOH = (size_t)E_ * C_ * H_ * 2;       // 1 MB
    const size_t SZ_ARR = (size_t)T_ * 256 * 4;           // arrival slots (256 KB)
    const size_t SZ_GO2 = (size_t)T_ * 16 * 16 * 16 * 4;  // per-tile go lines (4 MB)
    const size_t SZ_WIH = (size_t)E_ * G4 * I_ * 2;       // 33.5 MB (optional)
    const size_t SZ_XH  = (size_t)T_ * B_ * I_ * 2;       // 33.5 MB (optional)

    f16*   xi     = (f16*)carve(SZ_XI);
    f16*   Woh    = (f16*)carve(SZ_WOH);
    f16*   h0h    = (f16*)carve((size_t)B_ * H_ * 2);
    float* gbias  = (float*)carve((size_t)B_ * G4 * 4);
    float* bom    = (float*)carve((size_t)B_ * C_ * 4);
    int*   arr    = (int*)carve(SZ_ARR);
    int*   go2    = (int*)carve(SZ_GO2);

    f16* Wih = nullptr;
    f16* xh  = nullptr;
    if (off + SZ_WIH + 256 <= ws_size) Wih = (f16*)carve(SZ_WIH);
    if (Wih && off + SZ_XH + 256 <= ws_size) xh = (f16*)carve(SZ_XH);
    (void)in_sizes; (void)n_in; (void)out_size;

    hipMemsetAsync(arr, 0, SZ_ARR, stream);
    hipMemsetAsync(go2, 0, SZ_GO2, stream);

    if (xh)  k_f32_to_f16<<<2048, 256, 0, stream>>>(x,  xh,  (T_ * B_ * I_) / 8);
    if (Wih) k_f32_to_f16<<<2048, 256, 0, stream>>>(Wi, Wih, (E_ * G4 * I_) / 8);
    k_f32_to_f16<<<512,  256, 0, stream>>>(Wo, Woh, (E_ * C_ * H_) / 8);
    k_mix_biases<<<512, 256, 0, stream>>>(coef, bi, bh, bo, gbias, bom);
    k_init_h0h<<<(B_ * H_ + 255) / 256, 256, 0, stream>>>(h0, h0h);

    dim3 gx(32, 64);
    if (xh)
        k_xi_gemm<true,  true ><<<gx, 256, 0, stream>>>(xh, nullptr, Wih, nullptr, coef, gbias, xi);
    else if (Wih)
        k_xi_gemm<false, true ><<<gx, 256, 0, stream>>>(nullptr, x, Wih, nullptr, coef, gbias, xi);
    else
        k_xi_gemm<false, false><<<gx, 256, 0, stream>>>(nullptr, x, nullptr, Wi, coef, gbias, xi);

    // persistent recurrence: one cooperative launch, 256 blocks x 512 threads
    {
        void* args[] = { (void*)&Wh, (void*)&h0h, (void*)&c0, (void*)&xi,
                         (void*)&coef, (void*)&out, (void*)&arr, (void*)&go2 };
        hipLaunchCooperativeKernel((const void*)k_rec_persist, dim3(256), dim3(512),
                                   args, 0, stream);
    }

    dim3 go_(2, 256);
    k_out_gemm<<<go_, 256, 0, stream>>>(xi, Woh, coef, bom, out);
}